// Round 6
// baseline (16008.142 us; speedup 1.0000x reference)
//
#include <hip/hip_runtime.h>
#include <math.h>

#define BB 64
#define STT 512
#define SLL 64
#define DD 256
#define HH 256
#define HB 16384  // HH*BB elements per h-slab

typedef __bf16 v8bf __attribute__((ext_vector_type(8)));
typedef float f32x16 __attribute__((ext_vector_type(16)));
typedef unsigned long long u64;

#define MFMA(a, b, c) __builtin_amdgcn_mfma_f32_32x32x16_bf16(a, b, c, 0, 0, 0)

__device__ __forceinline__ float sigm(float x) { return 1.0f / (1.0f + __expf(-x)); }
__device__ __forceinline__ v8bf ldv(const __bf16* p) { return *(const v8bf*)p; }
__device__ __forceinline__ __bf16 bfbits(unsigned short u) {
  return __builtin_bit_cast(__bf16, u);
}

__device__ __forceinline__ void unpack8(uint4 qa, uint4 qb, v8bf& hi, v8bf& lo) {
  unsigned wa[4] = {qa.x, qa.y, qa.z, qa.w};
  unsigned wb[4] = {qb.x, qb.y, qb.z, qb.w};
#pragma unroll
  for (int e = 0; e < 4; ++e) {
    hi[e] = bfbits((unsigned short)(wa[e] & 0xffff));
    lo[e] = bfbits((unsigned short)(wa[e] >> 16));
    hi[4 + e] = bfbits((unsigned short)(wb[e] & 0xffff));
    lo[4 + e] = bfbits((unsigned short)(wb[e] >> 16));
  }
}

struct PArgs {
  const __bf16* xhi[4];
  const __bf16* xlo[4];
  const float* mv[4];
  const float* whh[4];
  const float* wih[4];
  const float* bih[4];
  const float* bhh[4];
  float* hs[4];
  unsigned* hx[4];  // packed (lo<<16 | hi) bf16 pair, [2 slots][B][HH]
  unsigned* sync;   // per-kernel 4KB; stream s uses u32 [s*256 .. s*256+256)
  int T[4];
  int dir[4];
};

// Persistent BiLSTM. Grid = 32 blocks x 256 threads.
// stream s = blockIdx&3, unit-block jb = blockIdx>>2 (32 hidden units each).
// No placement assumptions: h exchange + step barrier use agent-scope atomics
// (correct across XCDs; round-2-validated protocol). Weights stay in VGPR/AGPR
// as split-bf16 MFMA B-fragments. h_{t-1} staged to LDS once per block per
// step (single 64KB MLP'd load, kills 4x per-wave redundancy). For ctx
// (XMODE 0) the x-projection MFMAs for step t+1 run between signal(t) and
// poll(t) to hide peers' latency.
template <int XMODE>
__global__ __launch_bounds__(256, 1) void lstm_persist(PArgs A) {
  const int s = blockIdx.x & 3;
  const int jb = blockIdx.x >> 2;
  const int T = A.T[s];
  const int dir = A.dir[s];
  const int tid = threadIdx.x;
  const int lane = tid & 63;
  const int g = tid >> 6;              // gate type of this wave
  const int l31 = lane & 31;
  const int khalf = (lane >> 5) << 3;  // 0 or 8 (A-frag k-offset)
  const int u_base = jb * 32;

  __shared__ u64 stage64[64][128];     // h_{t-1}, XOR-swizzled 16B granules
  __shared__ float lds_g[4][64][32];
  __shared__ float bias_s[4][32];
  __shared__ float w0_s[4][32];
  __shared__ float w1_s[4][32];

  if (tid < 128) {
    int gg = tid >> 5, uu = tid & 31;
    int row = gg * 256 + u_base + uu;
    bias_s[gg][uu] = A.bih[s][row] + A.bhh[s][row];
    if (XMODE == 1) {
      w0_s[gg][uu] = A.wih[s][row * 2 + 0];
      w1_s[gg][uu] = A.wih[s][row * 2 + 1];
    }
  }

  // ---- register-resident split-bf16 B-fragments (Whh; Wih too for ctx) ----
  v8bf whhhi[16], whhlo[16], wihhi[16], wihlo[16];
  {
    const int row = g * 256 + u_base + l31;
    const float* rp = A.whh[s] + (size_t)row * 256 + khalf;
#pragma unroll
    for (int kt = 0; kt < 16; ++kt) {
      float4 q0 = *(const float4*)(rp + kt * 16);
      float4 q1 = *(const float4*)(rp + kt * 16 + 4);
      float vv[8] = {q0.x, q0.y, q0.z, q0.w, q1.x, q1.y, q1.z, q1.w};
#pragma unroll
      for (int e = 0; e < 8; ++e) {
        __bf16 hh = (__bf16)vv[e];
        whhhi[kt][e] = hh;
        whhlo[kt][e] = (__bf16)(vv[e] - (float)hh);
      }
    }
    if (XMODE == 0) {
      const float* rq = A.wih[s] + (size_t)row * 256 + khalf;
#pragma unroll
      for (int kt = 0; kt < 16; ++kt) {
        float4 q0 = *(const float4*)(rq + kt * 16);
        float4 q1 = *(const float4*)(rq + kt * 16 + 4);
        float vv[8] = {q0.x, q0.y, q0.z, q0.w, q1.x, q1.y, q1.z, q1.w};
#pragma unroll
        for (int e = 0; e < 8; ++e) {
          __bf16 hh = (__bf16)vv[e];
          wihhi[kt][e] = hh;
          wihlo[kt][e] = (__bf16)(vv[e] - (float)hh);
        }
      }
    }
  }

  float c[8];
#pragma unroll
  for (int p = 0; p < 8; ++p) c[p] = 0.f;

  const int u = tid & 31, bb0 = tid >> 5;  // combine-phase mapping
  unsigned* slots = A.sync + s * 256;      // 8 slots, 32 u32 (128B) apart

  // staging geometry: thread covers row r (batch), quarter q (32 u64)
  const int sr = tid >> 2;
  const int sq = tid & 3;

  // x-projection accumulators (ctx): computed one step ahead
  f32x16 xacc0 = (f32x16)(0.0f);
  f32x16 xacc1 = (f32x16)(0.0f);

  auto xproj = [&](int t, f32x16& xa0, f32x16& xa1) {
    const int m0 = (dir ? (T - 1 - t) : t) * 64;
    const __bf16* xh = A.xhi[s] + (size_t)m0 * 256;
    const __bf16* xl = A.xlo[s] + (size_t)m0 * 256;
#pragma unroll
    for (int kt = 0; kt < 16; ++kt) {
      const int ko = kt * 16 + khalf;
      v8bf xh0 = ldv(xh + (size_t)l31 * 256 + ko);
      v8bf xl0 = ldv(xl + (size_t)l31 * 256 + ko);
      v8bf xh1 = ldv(xh + (size_t)(l31 + 32) * 256 + ko);
      v8bf xl1 = ldv(xl + (size_t)(l31 + 32) * 256 + ko);
      xa0 = MFMA(xh0, wihhi[kt], xa0);
      xa0 = MFMA(xl0, wihhi[kt], xa0);
      xa0 = MFMA(xh0, wihlo[kt], xa0);
      xa1 = MFMA(xh1, wihhi[kt], xa1);
      xa1 = MFMA(xl1, wihhi[kt], xa1);
      xa1 = MFMA(xh1, wihlo[kt], xa1);
    }
  };

  __syncthreads();
  if (XMODE == 0) xproj(0, xacc0, xacc1);

  for (int t = 0; t < T; ++t) {
    f32x16 acc0 = xacc0;
    f32x16 acc1 = xacc1;

    if (t > 0) {
      // ---- wait for h_{t-1} from all 8 blocks of this stream ----
      const unsigned want = (unsigned)t;
      if (tid < 64) {
        for (;;) {
          unsigned v = __hip_atomic_load(&slots[(lane & 7) * 32], __ATOMIC_ACQUIRE,
                                         __HIP_MEMORY_SCOPE_AGENT);
          if (!__any(v < want)) break;
          __builtin_amdgcn_s_sleep(1);
        }
      }
      __syncthreads();

      // ---- stage h_{t-1} -> LDS (one 64KB load, 32 u64 MLP per thread) ----
      {
        const u64* hp = (const u64*)(A.hx[s] + ((t + 1) & 1) * HB) + sr * 128 + sq * 32;
        u64 v[32];
#pragma unroll
        for (int j = 0; j < 32; ++j)
          v[j] = __hip_atomic_load(hp + j, __ATOMIC_RELAXED, __HIP_MEMORY_SCOPE_AGENT);
#pragma unroll
        for (int j = 0; j < 32; j += 2) {
          int gi = (sq * 16 + (j >> 1)) ^ (sr & 7);
          stage64[sr][gi * 2] = v[j];
          stage64[sr][gi * 2 + 1] = v[j + 1];
        }
      }
      __syncthreads();

      // ---- h MFMAs from staged LDS ----
      const int rswz = l31 & 7;  // same for rows l31 and l31+32
#pragma unroll
      for (int kt = 0; kt < 16; ++kt) {
        const int gbase = kt * 4 + (khalf >> 2);
        const int g0 = (gbase ^ rswz) * 2;
        const int g1 = ((gbase + 1) ^ rswz) * 2;
        uint4 qa0 = *(const uint4*)&stage64[l31][g0];
        uint4 qb0 = *(const uint4*)&stage64[l31][g1];
        uint4 qa1 = *(const uint4*)&stage64[l31 + 32][g0];
        uint4 qb1 = *(const uint4*)&stage64[l31 + 32][g1];
        v8bf ah0, al0, ah1, al1;
        unpack8(qa0, qb0, ah0, al0);
        unpack8(qa1, qb1, ah1, al1);
        acc0 = MFMA(ah0, whhhi[kt], acc0);
        acc0 = MFMA(al0, whhhi[kt], acc0);
        acc0 = MFMA(ah0, whhlo[kt], acc0);
        acc1 = MFMA(ah1, whhhi[kt], acc1);
        acc1 = MFMA(al1, whhhi[kt], acc1);
        acc1 = MFMA(ah1, whhlo[kt], acc1);
      }
    }

    // C/D layout (32x32): col=lane&31, row=(r&3)+8*(r>>2)+4*(lane>>5)
#pragma unroll
    for (int r = 0; r < 16; ++r) {
      int m = (r & 3) + 8 * (r >> 2) + 4 * (lane >> 5);
      lds_g[g][m][l31] = acc0[r];
      lds_g[g][m + 32][l31] = acc1[r];
    }
    __syncthreads();

    unsigned* ho = A.hx[s] + (t & 1) * HB;
    float* hsout = A.hs[s] + (size_t)t * HB;
    const int t_eff = dir ? (T - 1 - t) : t;
#pragma unroll
    for (int p = 0; p < 8; ++p) {
      int b = p * 8 + bb0;
      float g0 = lds_g[0][b][u] + bias_s[0][u];
      float g1 = lds_g[1][b][u] + bias_s[1][u];
      float g2 = lds_g[2][b][u] + bias_s[2][u];
      float g3 = lds_g[3][b][u] + bias_s[3][u];
      if (XMODE == 1) {
        float m0 = A.mv[s][t_eff * 128 + b];
        float m1 = A.mv[s][t_eff * 128 + 64 + b];
        g0 += w0_s[0][u] * m0 + w1_s[0][u] * m1;
        g1 += w0_s[1][u] * m0 + w1_s[1][u] * m1;
        g2 += w0_s[2][u] * m0 + w1_s[2][u] * m1;
        g3 += w0_s[3][u] * m0 + w1_s[3][u] * m1;
      }
      float iv = sigm(g0), fv = sigm(g1), zv = tanhf(g2), ov = sigm(g3);
      float cn = fv * c[p] + iv * zv;
      c[p] = cn;
      float hv = ov * tanhf(cn);
      int ug = u_base + u;
      unsigned short hb_ = __builtin_bit_cast(unsigned short, (__bf16)hv);
      float hif = (float)bfbits(hb_);
      unsigned short lb_ = __builtin_bit_cast(unsigned short, (__bf16)(hv - hif));
      unsigned pack = ((unsigned)lb_ << 16) | (unsigned)hb_;
      __hip_atomic_store(&ho[(size_t)b * 256 + ug], pack, __ATOMIC_RELAXED,
                         __HIP_MEMORY_SCOPE_AGENT);
      if (XMODE == 0 || t == T - 1) hsout[(size_t)b * 256 + ug] = hv;
    }
    __syncthreads();  // drains each wave's agent stores (vmcnt(0) before barrier)

    // ---- signal own slot, then hide peers' latency behind x-projection ----
    if (tid == 0)
      __hip_atomic_store(&slots[jb * 32], (unsigned)(t + 1), __ATOMIC_RELEASE,
                         __HIP_MEMORY_SCOPE_AGENT);
    xacc0 = (f32x16)(0.0f);
    xacc1 = (f32x16)(0.0f);
    if (XMODE == 0 && t + 1 < T) xproj(t + 1, xacc0, xacc1);
  }
}

// x split-bf16 gather: xhi/xlo[m=t*64+b][k] = emb[tok[b][t]][k]
__global__ __launch_bounds__(256) void gather_split(const int* __restrict__ tok,
                                                    const float* __restrict__ emb,
                                                    __bf16* __restrict__ xhi,
                                                    __bf16* __restrict__ xlo, int T) {
  size_t idx = (size_t)blockIdx.x * 256 + threadIdx.x;
  int k = idx & 255;
  size_t m = idx >> 8;
  int b = (int)(m & 63);
  int t = (int)(m >> 6);
  int token = tok[b * T + t];
  float v = emb[(size_t)token * 256 + k];
  __bf16 h = (__bf16)v;
  xhi[idx] = h;
  xlo[idx] = (__bf16)(v - (float)h);
}

// hs layout: [t][b][256]. Thread b streams its 1KB row.
__global__ __launch_bounds__(256) void mv_match(const float* __restrict__ hsf,
                                                const float* __restrict__ hsb,
                                                const float* __restrict__ vf,
                                                const float* __restrict__ vb,
                                                const float* __restrict__ w1,
                                                const float* __restrict__ w2,
                                                float* __restrict__ mv, int T) {
  int b = threadIdx.x & 63;
  int t = blockIdx.x * 4 + (threadIdx.x >> 6);
  if (t >= T) return;
  {
    const float* v1 = hsf + ((size_t)t * 64 + b) * 256;
    const float* v2 = vf + (size_t)b * 256;
    float num = 0.f, na = 0.f, nb = 0.f;
#pragma unroll 4
    for (int k = 0; k < HH; ++k) {
      float w = w1[k];
      float av = w * v1[k];
      float bv = w * v2[k];
      num = fmaf(av, bv, num);
      na = fmaf(av, av, na);
      nb = fmaf(bv, bv, nb);
    }
    mv[((size_t)t * 2 + 0) * BB + b] = num / fmaxf(sqrtf(na) * sqrtf(nb), 1e-8f);
  }
  {
    const float* v1 = hsb + ((size_t)(T - 1 - t) * 64 + b) * 256;
    const float* v2 = vb + (size_t)b * 256;
    float num = 0.f, na = 0.f, nb = 0.f;
#pragma unroll 4
    for (int k = 0; k < HH; ++k) {
      float w = w2[k];
      float av = w * v1[k];
      float bv = w * v2[k];
      num = fmaf(av, bv, num);
      na = fmaf(av, av, na);
      nb = fmaf(bv, bv, nb);
    }
    mv[((size_t)t * 2 + 1) * BB + b] = num / fmaxf(sqrtf(na) * sqrtf(nb), 1e-8f);
  }
}

// finals layout: [b][256]
__global__ __launch_bounds__(256) void final_fc(const float* __restrict__ pf,
                                                const float* __restrict__ pb,
                                                const float* __restrict__ hf,
                                                const float* __restrict__ hb,
                                                const float* __restrict__ fc1W,
                                                const float* __restrict__ fc1b,
                                                const float* __restrict__ fc2W,
                                                const float* __restrict__ fc2b,
                                                float* __restrict__ out) {
  __shared__ float xs[1024];
  __shared__ float ys[512];
  int b = blockIdx.x;
  for (int i = threadIdx.x; i < 1024; i += 256) {
    const float* src = (i < 256) ? pf : (i < 512) ? pb : (i < 768) ? hf : hb;
    xs[i] = src[(size_t)b * 256 + (i & 255)];
  }
  __syncthreads();
  for (int o = threadIdx.x; o < 512; o += 256) {
    float acc = fc1b[o];
    const float* w = fc1W + (size_t)o * 1024;
#pragma unroll 4
    for (int k = 0; k < 1024; ++k) acc = fmaf(w[k], xs[k], acc);
    ys[o] = tanhf(acc);
  }
  __syncthreads();
  if (threadIdx.x < 20) {
    int o = threadIdx.x;
    float acc = fc2b[o];
    const float* w = fc2W + (size_t)o * 512;
#pragma unroll 4
    for (int k = 0; k < 512; ++k) acc = fmaf(w[k], ys[k], acc);
    out[b * 20 + o] = acc;
  }
}

__global__ void guard_fill(float* out, int n, float v) {
  int i = blockIdx.x * 256 + threadIdx.x;
  if (i < n) out[i] = v;
}

extern "C" void kernel_launch(void* const* d_in, const int* in_sizes, int n_in,
                              void* d_out, int out_size, void* d_ws, size_t ws_size,
                              hipStream_t stream) {
  const int* text = (const int*)d_in[0];
  const int* label = (const int*)d_in[1];
  const float* emb = (const float*)d_in[2];
  const float* cWih_f = (const float*)d_in[3];
  const float* cWhh_f = (const float*)d_in[4];
  const float* cbih_f = (const float*)d_in[5];
  const float* cbhh_f = (const float*)d_in[6];
  const float* cWih_b = (const float*)d_in[7];
  const float* cWhh_b = (const float*)d_in[8];
  const float* cbih_b = (const float*)d_in[9];
  const float* cbhh_b = (const float*)d_in[10];
  const float* w1 = (const float*)d_in[11];
  const float* w2 = (const float*)d_in[12];
  const float* aWih_f = (const float*)d_in[13];
  const float* aWhh_f = (const float*)d_in[14];
  const float* abih_f = (const float*)d_in[15];
  const float* abhh_f = (const float*)d_in[16];
  const float* aWih_b = (const float*)d_in[17];
  const float* aWhh_b = (const float*)d_in[18];
  const float* abih_b = (const float*)d_in[19];
  const float* abhh_b = (const float*)d_in[20];
  const float* fc1W = (const float*)d_in[21];
  const float* fc1b = (const float*)d_in[22];
  const float* fc2W = (const float*)d_in[23];
  const float* fc2b = (const float*)d_in[24];
  float* out = (float*)d_out;

  char* base = (char*)d_ws;
  size_t off = 0;
  auto alloc = [&](size_t bytes) {
    void* p = base + off;
    off = (off + bytes + 255) & ~(size_t)255;
    return p;
  };

  __bf16* xp_hi = (__bf16*)alloc((size_t)STT * 64 * 256 * 2);
  __bf16* xp_lo = (__bf16*)alloc((size_t)STT * 64 * 256 * 2);
  __bf16* xh_hi = (__bf16*)alloc((size_t)SLL * 64 * 256 * 2);
  __bf16* xh_lo = (__bf16*)alloc((size_t)SLL * 64 * 256 * 2);
  float* hs_pf = (float*)alloc((size_t)STT * HB * 4);
  float* hs_pb = (float*)alloc((size_t)STT * HB * 4);
  float* hs_hf = (float*)alloc((size_t)SLL * HB * 4);
  float* hs_hb = (float*)alloc((size_t)SLL * HB * 4);
  float* mv_p = (float*)alloc((size_t)STT * 2 * 64 * 4);
  float* mv_h = (float*)alloc((size_t)SLL * 2 * 64 * 4);
  // ---- zeroed-per-launch region: hx (8 stream-slots x 2 x HB u32) + sync ----
  size_t zero_off = off;
  unsigned* hxbase = (unsigned*)alloc((size_t)8 * 2 * HB * 4);
  unsigned* sync_ctx = (unsigned*)alloc(4096);
  unsigned* sync_agg = (unsigned*)alloc(4096);
  size_t zero_len = off - zero_off;

  if (ws_size < off) {
    guard_fill<<<(out_size + 255) / 256, 256, 0, stream>>>(out, out_size,
                                                           (float)(ws_size >> 20));
    return;
  }

  hipMemsetAsync(base + zero_off, 0, zero_len, stream);

  gather_split<<<(STT * 64 * 256) / 256, 256, 0, stream>>>(text, emb, xp_hi, xp_lo, STT);
  gather_split<<<(SLL * 64 * 256) / 256, 256, 0, stream>>>(label, emb, xh_hi, xh_lo, SLL);

  PArgs cx;
  for (int s = 0; s < 4; ++s) {
    cx.xhi[s] = (s < 2) ? xp_hi : xh_hi;
    cx.xlo[s] = (s < 2) ? xp_lo : xh_lo;
    cx.mv[s] = nullptr;
    cx.whh[s] = (s & 1) ? cWhh_b : cWhh_f;
    cx.wih[s] = (s & 1) ? cWih_b : cWih_f;
    cx.bih[s] = (s & 1) ? cbih_b : cbih_f;
    cx.bhh[s] = (s & 1) ? cbhh_b : cbhh_f;
    cx.hx[s] = hxbase + (size_t)s * 2 * HB;
    cx.T[s] = (s < 2) ? STT : SLL;
    cx.dir[s] = s & 1;
  }
  cx.hs[0] = hs_pf; cx.hs[1] = hs_pb; cx.hs[2] = hs_hf; cx.hs[3] = hs_hb;
  cx.sync = sync_ctx;
  lstm_persist<0><<<32, 256, 0, stream>>>(cx);

  mv_match<<<STT / 4, 256, 0, stream>>>(hs_pf, hs_pb, hs_hf + (size_t)(SLL - 1) * HB,
                                        hs_hb + (size_t)(SLL - 1) * HB, w1, w2, mv_p, STT);
  mv_match<<<SLL / 4, 256, 0, stream>>>(hs_hf, hs_hb, hs_pf + (size_t)(STT - 1) * HB,
                                        hs_pb + (size_t)(STT - 1) * HB, w1, w2, mv_h, SLL);

  PArgs ag;
  for (int s = 0; s < 4; ++s) {
    ag.xhi[s] = nullptr;
    ag.xlo[s] = nullptr;
    ag.mv[s] = (s < 2) ? mv_p : mv_h;
    ag.whh[s] = (s & 1) ? aWhh_b : aWhh_f;
    ag.wih[s] = (s & 1) ? aWih_b : aWih_f;
    ag.bih[s] = (s & 1) ? abih_b : abih_f;
    ag.bhh[s] = (s & 1) ? abhh_b : abhh_f;
    ag.hx[s] = hxbase + (size_t)(4 + s) * 2 * HB;
    ag.T[s] = (s < 2) ? STT : SLL;
    ag.dir[s] = s & 1;
  }
  // agg writes hs only at t=T-1 (finals); reuse ctx hs buffers
  ag.hs[0] = hs_pf; ag.hs[1] = hs_pb; ag.hs[2] = hs_hf; ag.hs[3] = hs_hb;
  ag.sync = sync_agg;
  lstm_persist<1><<<32, 256, 0, stream>>>(ag);

  final_fc<<<BB, 256, 0, stream>>>(hs_pf + (size_t)(STT - 1) * HB,
                                   hs_pb + (size_t)(STT - 1) * HB,
                                   hs_hf + (size_t)(SLL - 1) * HB,
                                   hs_hb + (size_t)(SLL - 1) * HB,
                                   fc1W, fc1b, fc2W, fc2b, out);
}

// Round 7
// 15965.384 us; speedup vs baseline: 1.0027x; 1.0027x over previous
//
#include <hip/hip_runtime.h>
#include <math.h>

#define BB 64
#define STT 512
#define SLL 64
#define DD 256
#define HH 256
#define HB 16384  // HH*BB elements per h-slab

typedef __bf16 v8bf __attribute__((ext_vector_type(8)));
typedef float f32x16 __attribute__((ext_vector_type(16)));
typedef unsigned long long u64;

#define MFMA(a, b, c) __builtin_amdgcn_mfma_f32_32x32x16_bf16(a, b, c, 0, 0, 0)

__device__ __forceinline__ float sigm(float x) { return 1.0f / (1.0f + __expf(-x)); }
__device__ __forceinline__ v8bf ldv(const __bf16* p) { return *(const v8bf*)p; }
__device__ __forceinline__ __bf16 bfbits(unsigned short u) {
  return __builtin_bit_cast(__bf16, u);
}

__device__ __forceinline__ void unpack8(uint4 qa, uint4 qb, v8bf& hi, v8bf& lo) {
  unsigned wa[4] = {qa.x, qa.y, qa.z, qa.w};
  unsigned wb[4] = {qb.x, qb.y, qb.z, qb.w};
#pragma unroll
  for (int e = 0; e < 4; ++e) {
    hi[e] = bfbits((unsigned short)(wa[e] & 0xffff));
    lo[e] = bfbits((unsigned short)(wa[e] >> 16));
    hi[4 + e] = bfbits((unsigned short)(wb[e] & 0xffff));
    lo[4 + e] = bfbits((unsigned short)(wb[e] >> 16));
  }
}

struct PArgs {
  const __bf16* xhi[4];
  const __bf16* xlo[4];
  const float* mv[4];
  const float* whh[4];
  const float* wih[4];
  const float* bih[4];
  const float* bhh[4];
  float* hs[4];
  unsigned* hx[4];  // packed (lo<<16 | hi) bf16 pair, [2 slots][B][HH]
  unsigned* sync;   // per-kernel 4KB; stream s uses u32 [s*256 .. s*256+256)
  int T[4];
  int dir[4];
};

// Persistent BiLSTM. Grid = 32 blocks x 256 threads.
// stream s = blockIdx&3, unit-block jb = blockIdx>>2 (32 hidden units each).
// No placement assumptions: h exchange + step barrier use agent-scope atomics
// (correct across XCDs; round-2-validated protocol). Weights stay in VGPR/AGPR
// as split-bf16 MFMA B-fragments. h_{t-1} staged to LDS once per block per
// step (single 64KB MLP'd load, kills 4x per-wave redundancy). For ctx
// (XMODE 0) the x-projection MFMAs for step t+1 run between signal(t) and
// poll(t) to hide peers' latency.
template <int XMODE>
__global__ __launch_bounds__(256, 1) void lstm_persist(PArgs A) {
  const int s = blockIdx.x & 3;
  const int jb = blockIdx.x >> 2;
  const int T = A.T[s];
  const int dir = A.dir[s];
  const int tid = threadIdx.x;
  const int lane = tid & 63;
  const int g = tid >> 6;              // gate type of this wave
  const int l31 = lane & 31;
  const int khalf = (lane >> 5) << 3;  // 0 or 8 (A-frag k-offset)
  const int u_base = jb * 32;

  __shared__ u64 stage64[64][128];     // h_{t-1}, XOR-swizzled 16B granules
  __shared__ float lds_g[4][64][32];
  __shared__ float bias_s[4][32];
  __shared__ float w0_s[4][32];
  __shared__ float w1_s[4][32];

  if (tid < 128) {
    int gg = tid >> 5, uu = tid & 31;
    int row = gg * 256 + u_base + uu;
    bias_s[gg][uu] = A.bih[s][row] + A.bhh[s][row];
    if (XMODE == 1) {
      w0_s[gg][uu] = A.wih[s][row * 2 + 0];
      w1_s[gg][uu] = A.wih[s][row * 2 + 1];
    }
  }

  // ---- register-resident split-bf16 B-fragments (Whh; Wih too for ctx) ----
  v8bf whhhi[16], whhlo[16], wihhi[16], wihlo[16];
  {
    const int row = g * 256 + u_base + l31;
    const float* rp = A.whh[s] + (size_t)row * 256 + khalf;
#pragma unroll
    for (int kt = 0; kt < 16; ++kt) {
      float4 q0 = *(const float4*)(rp + kt * 16);
      float4 q1 = *(const float4*)(rp + kt * 16 + 4);
      float vv[8] = {q0.x, q0.y, q0.z, q0.w, q1.x, q1.y, q1.z, q1.w};
#pragma unroll
      for (int e = 0; e < 8; ++e) {
        __bf16 hh = (__bf16)vv[e];
        whhhi[kt][e] = hh;
        whhlo[kt][e] = (__bf16)(vv[e] - (float)hh);
      }
    }
    if (XMODE == 0) {
      const float* rq = A.wih[s] + (size_t)row * 256 + khalf;
#pragma unroll
      for (int kt = 0; kt < 16; ++kt) {
        float4 q0 = *(const float4*)(rq + kt * 16);
        float4 q1 = *(const float4*)(rq + kt * 16 + 4);
        float vv[8] = {q0.x, q0.y, q0.z, q0.w, q1.x, q1.y, q1.z, q1.w};
#pragma unroll
        for (int e = 0; e < 8; ++e) {
          __bf16 hh = (__bf16)vv[e];
          wihhi[kt][e] = hh;
          wihlo[kt][e] = (__bf16)(vv[e] - (float)hh);
        }
      }
    }
  }

  float c[8];
#pragma unroll
  for (int p = 0; p < 8; ++p) c[p] = 0.f;

  const int u = tid & 31, bb0 = tid >> 5;  // combine-phase mapping
  unsigned* slots = A.sync + s * 256;      // 8 slots, 32 u32 (128B) apart

  // staging geometry: thread covers row r (batch), quarter q (32 u64)
  const int sr = tid >> 2;
  const int sq = tid & 3;

  // x-projection accumulators (ctx): computed one step ahead
  f32x16 xacc0 = (f32x16)(0.0f);
  f32x16 xacc1 = (f32x16)(0.0f);

  auto xproj = [&](int t, f32x16& xa0, f32x16& xa1) {
    const int m0 = (dir ? (T - 1 - t) : t) * 64;
    const __bf16* xh = A.xhi[s] + (size_t)m0 * 256;
    const __bf16* xl = A.xlo[s] + (size_t)m0 * 256;
#pragma unroll
    for (int kt = 0; kt < 16; ++kt) {
      const int ko = kt * 16 + khalf;
      v8bf xh0 = ldv(xh + (size_t)l31 * 256 + ko);
      v8bf xl0 = ldv(xl + (size_t)l31 * 256 + ko);
      v8bf xh1 = ldv(xh + (size_t)(l31 + 32) * 256 + ko);
      v8bf xl1 = ldv(xl + (size_t)(l31 + 32) * 256 + ko);
      xa0 = MFMA(xh0, wihhi[kt], xa0);
      xa0 = MFMA(xl0, wihhi[kt], xa0);
      xa0 = MFMA(xh0, wihlo[kt], xa0);
      xa1 = MFMA(xh1, wihhi[kt], xa1);
      xa1 = MFMA(xl1, wihhi[kt], xa1);
      xa1 = MFMA(xh1, wihlo[kt], xa1);
    }
  };

  __syncthreads();
  if (XMODE == 0) xproj(0, xacc0, xacc1);

  for (int t = 0; t < T; ++t) {
    f32x16 acc0 = xacc0;
    f32x16 acc1 = xacc1;

    if (t > 0) {
      // ---- wait for h_{t-1} from all 8 blocks of this stream ----
      const unsigned want = (unsigned)t;
      if (tid < 64) {
        for (;;) {
          unsigned v = __hip_atomic_load(&slots[(lane & 7) * 32], __ATOMIC_ACQUIRE,
                                         __HIP_MEMORY_SCOPE_AGENT);
          if (!__any(v < want)) break;
          __builtin_amdgcn_s_sleep(1);
        }
      }
      __syncthreads();

      // ---- stage h_{t-1} -> LDS (one 64KB load, 32 u64 MLP per thread) ----
      {
        const u64* hp = (const u64*)(A.hx[s] + ((t + 1) & 1) * HB) + sr * 128 + sq * 32;
        u64 v[32];
#pragma unroll
        for (int j = 0; j < 32; ++j)
          v[j] = __hip_atomic_load(hp + j, __ATOMIC_RELAXED, __HIP_MEMORY_SCOPE_AGENT);
#pragma unroll
        for (int j = 0; j < 32; j += 2) {
          int gi = (sq * 16 + (j >> 1)) ^ (sr & 7);
          stage64[sr][gi * 2] = v[j];
          stage64[sr][gi * 2 + 1] = v[j + 1];
        }
      }
      __syncthreads();

      // ---- h MFMAs from staged LDS ----
      const int rswz = l31 & 7;  // same for rows l31 and l31+32
#pragma unroll
      for (int kt = 0; kt < 16; ++kt) {
        const int gbase = kt * 4 + (khalf >> 2);
        const int g0 = (gbase ^ rswz) * 2;
        const int g1 = ((gbase + 1) ^ rswz) * 2;
        uint4 qa0 = *(const uint4*)&stage64[l31][g0];
        uint4 qb0 = *(const uint4*)&stage64[l31][g1];
        uint4 qa1 = *(const uint4*)&stage64[l31 + 32][g0];
        uint4 qb1 = *(const uint4*)&stage64[l31 + 32][g1];
        v8bf ah0, al0, ah1, al1;
        unpack8(qa0, qb0, ah0, al0);
        unpack8(qa1, qb1, ah1, al1);
        acc0 = MFMA(ah0, whhhi[kt], acc0);
        acc0 = MFMA(al0, whhhi[kt], acc0);
        acc0 = MFMA(ah0, whhlo[kt], acc0);
        acc1 = MFMA(ah1, whhhi[kt], acc1);
        acc1 = MFMA(al1, whhhi[kt], acc1);
        acc1 = MFMA(ah1, whhlo[kt], acc1);
      }
    }

    // C/D layout (32x32): col=lane&31, row=(r&3)+8*(r>>2)+4*(lane>>5)
#pragma unroll
    for (int r = 0; r < 16; ++r) {
      int m = (r & 3) + 8 * (r >> 2) + 4 * (lane >> 5);
      lds_g[g][m][l31] = acc0[r];
      lds_g[g][m + 32][l31] = acc1[r];
    }
    __syncthreads();

    unsigned* ho = A.hx[s] + (t & 1) * HB;
    float* hsout = A.hs[s] + (size_t)t * HB;
    const int t_eff = dir ? (T - 1 - t) : t;
#pragma unroll
    for (int p = 0; p < 8; ++p) {
      int b = p * 8 + bb0;
      float g0 = lds_g[0][b][u] + bias_s[0][u];
      float g1 = lds_g[1][b][u] + bias_s[1][u];
      float g2 = lds_g[2][b][u] + bias_s[2][u];
      float g3 = lds_g[3][b][u] + bias_s[3][u];
      if (XMODE == 1) {
        float m0 = A.mv[s][t_eff * 128 + b];
        float m1 = A.mv[s][t_eff * 128 + 64 + b];
        g0 += w0_s[0][u] * m0 + w1_s[0][u] * m1;
        g1 += w0_s[1][u] * m0 + w1_s[1][u] * m1;
        g2 += w0_s[2][u] * m0 + w1_s[2][u] * m1;
        g3 += w0_s[3][u] * m0 + w1_s[3][u] * m1;
      }
      float iv = sigm(g0), fv = sigm(g1), zv = tanhf(g2), ov = sigm(g3);
      float cn = fv * c[p] + iv * zv;
      c[p] = cn;
      float hv = ov * tanhf(cn);
      int ug = u_base + u;
      unsigned short hb_ = __builtin_bit_cast(unsigned short, (__bf16)hv);
      float hif = (float)bfbits(hb_);
      unsigned short lb_ = __builtin_bit_cast(unsigned short, (__bf16)(hv - hif));
      unsigned pack = ((unsigned)lb_ << 16) | (unsigned)hb_;
      __hip_atomic_store(&ho[(size_t)b * 256 + ug], pack, __ATOMIC_RELAXED,
                         __HIP_MEMORY_SCOPE_AGENT);
      if (XMODE == 0 || t == T - 1) hsout[(size_t)b * 256 + ug] = hv;
    }
    __syncthreads();  // drains each wave's agent stores (vmcnt(0) before barrier)

    // ---- signal own slot, then hide peers' latency behind x-projection ----
    if (tid == 0)
      __hip_atomic_store(&slots[jb * 32], (unsigned)(t + 1), __ATOMIC_RELEASE,
                         __HIP_MEMORY_SCOPE_AGENT);
    xacc0 = (f32x16)(0.0f);
    xacc1 = (f32x16)(0.0f);
    if (XMODE == 0 && t + 1 < T) xproj(t + 1, xacc0, xacc1);
  }
}

// x split-bf16 gather: xhi/xlo[m=t*64+b][k] = emb[tok[b][t]][k]
__global__ __launch_bounds__(256) void gather_split(const int* __restrict__ tok,
                                                    const float* __restrict__ emb,
                                                    __bf16* __restrict__ xhi,
                                                    __bf16* __restrict__ xlo, int T) {
  size_t idx = (size_t)blockIdx.x * 256 + threadIdx.x;
  int k = idx & 255;
  size_t m = idx >> 8;
  int b = (int)(m & 63);
  int t = (int)(m >> 6);
  int token = tok[b * T + t];
  float v = emb[(size_t)token * 256 + k];
  __bf16 h = (__bf16)v;
  xhi[idx] = h;
  xlo[idx] = (__bf16)(v - (float)h);
}

// hs layout: [t][b][256]. Thread b streams its 1KB row.
__global__ __launch_bounds__(256) void mv_match(const float* __restrict__ hsf,
                                                const float* __restrict__ hsb,
                                                const float* __restrict__ vf,
                                                const float* __restrict__ vb,
                                                const float* __restrict__ w1,
                                                const float* __restrict__ w2,
                                                float* __restrict__ mv, int T) {
  int b = threadIdx.x & 63;
  int t = blockIdx.x * 4 + (threadIdx.x >> 6);
  if (t >= T) return;
  {
    const float* v1 = hsf + ((size_t)t * 64 + b) * 256;
    const float* v2 = vf + (size_t)b * 256;
    float num = 0.f, na = 0.f, nb = 0.f;
#pragma unroll 4
    for (int k = 0; k < HH; ++k) {
      float w = w1[k];
      float av = w * v1[k];
      float bv = w * v2[k];
      num = fmaf(av, bv, num);
      na = fmaf(av, av, na);
      nb = fmaf(bv, bv, nb);
    }
    mv[((size_t)t * 2 + 0) * BB + b] = num / fmaxf(sqrtf(na) * sqrtf(nb), 1e-8f);
  }
  {
    const float* v1 = hsb + ((size_t)(T - 1 - t) * 64 + b) * 256;
    const float* v2 = vb + (size_t)b * 256;
    float num = 0.f, na = 0.f, nb = 0.f;
#pragma unroll 4
    for (int k = 0; k < HH; ++k) {
      float w = w2[k];
      float av = w * v1[k];
      float bv = w * v2[k];
      num = fmaf(av, bv, num);
      na = fmaf(av, av, na);
      nb = fmaf(bv, bv, nb);
    }
    mv[((size_t)t * 2 + 1) * BB + b] = num / fmaxf(sqrtf(na) * sqrtf(nb), 1e-8f);
  }
}

// finals layout: [b][256]
__global__ __launch_bounds__(256) void final_fc(const float* __restrict__ pf,
                                                const float* __restrict__ pb,
                                                const float* __restrict__ hf,
                                                const float* __restrict__ hb,
                                                const float* __restrict__ fc1W,
                                                const float* __restrict__ fc1b,
                                                const float* __restrict__ fc2W,
                                                const float* __restrict__ fc2b,
                                                float* __restrict__ out) {
  __shared__ float xs[1024];
  __shared__ float ys[512];
  int b = blockIdx.x;
  for (int i = threadIdx.x; i < 1024; i += 256) {
    const float* src = (i < 256) ? pf : (i < 512) ? pb : (i < 768) ? hf : hb;
    xs[i] = src[(size_t)b * 256 + (i & 255)];
  }
  __syncthreads();
  for (int o = threadIdx.x; o < 512; o += 256) {
    float acc = fc1b[o];
    const float* w = fc1W + (size_t)o * 1024;
#pragma unroll 4
    for (int k = 0; k < 1024; ++k) acc = fmaf(w[k], xs[k], acc);
    ys[o] = tanhf(acc);
  }
  __syncthreads();
  if (threadIdx.x < 20) {
    int o = threadIdx.x;
    float acc = fc2b[o];
    const float* w = fc2W + (size_t)o * 512;
#pragma unroll 4
    for (int k = 0; k < 512; ++k) acc = fmaf(w[k], ys[k], acc);
    out[b * 20 + o] = acc;
  }
}

__global__ void guard_fill(float* out, int n, float v) {
  int i = blockIdx.x * 256 + threadIdx.x;
  if (i < n) out[i] = v;
}

extern "C" void kernel_launch(void* const* d_in, const int* in_sizes, int n_in,
                              void* d_out, int out_size, void* d_ws, size_t ws_size,
                              hipStream_t stream) {
  const int* text = (const int*)d_in[0];
  const int* label = (const int*)d_in[1];
  const float* emb = (const float*)d_in[2];
  const float* cWih_f = (const float*)d_in[3];
  const float* cWhh_f = (const float*)d_in[4];
  const float* cbih_f = (const float*)d_in[5];
  const float* cbhh_f = (const float*)d_in[6];
  const float* cWih_b = (const float*)d_in[7];
  const float* cWhh_b = (const float*)d_in[8];
  const float* cbih_b = (const float*)d_in[9];
  const float* cbhh_b = (const float*)d_in[10];
  const float* w1 = (const float*)d_in[11];
  const float* w2 = (const float*)d_in[12];
  const float* aWih_f = (const float*)d_in[13];
  const float* aWhh_f = (const float*)d_in[14];
  const float* abih_f = (const float*)d_in[15];
  const float* abhh_f = (const float*)d_in[16];
  const float* aWih_b = (const float*)d_in[17];
  const float* aWhh_b = (const float*)d_in[18];
  const float* abih_b = (const float*)d_in[19];
  const float* abhh_b = (const float*)d_in[20];
  const float* fc1W = (const float*)d_in[21];
  const float* fc1b = (const float*)d_in[22];
  const float* fc2W = (const float*)d_in[23];
  const float* fc2b = (const float*)d_in[24];
  float* out = (float*)d_out;

  char* base = (char*)d_ws;
  size_t off = 0;
  auto alloc = [&](size_t bytes) {
    void* p = base + off;
    off = (off + bytes + 255) & ~(size_t)255;
    return p;
  };

  __bf16* xp_hi = (__bf16*)alloc((size_t)STT * 64 * 256 * 2);
  __bf16* xp_lo = (__bf16*)alloc((size_t)STT * 64 * 256 * 2);
  __bf16* xh_hi = (__bf16*)alloc((size_t)SLL * 64 * 256 * 2);
  __bf16* xh_lo = (__bf16*)alloc((size_t)SLL * 64 * 256 * 2);
  float* hs_pf = (float*)alloc((size_t)STT * HB * 4);
  float* hs_pb = (float*)alloc((size_t)STT * HB * 4);
  float* hs_hf = (float*)alloc((size_t)SLL * HB * 4);
  float* hs_hb = (float*)alloc((size_t)SLL * HB * 4);
  float* mv_p = (float*)alloc((size_t)STT * 2 * 64 * 4);
  float* mv_h = (float*)alloc((size_t)SLL * 2 * 64 * 4);
  // ---- zeroed-per-launch region: hx (8 stream-slots x 2 x HB u32) + sync ----
  size_t zero_off = off;
  unsigned* hxbase = (unsigned*)alloc((size_t)8 * 2 * HB * 4);
  unsigned* sync_ctx = (unsigned*)alloc(4096);
  unsigned* sync_agg = (unsigned*)alloc(4096);
  size_t zero_len = off - zero_off;

  if (ws_size < off) {
    guard_fill<<<(out_size + 255) / 256, 256, 0, stream>>>(out, out_size,
                                                           (float)(ws_size >> 20));
    return;
  }

  hipMemsetAsync(base + zero_off, 0, zero_len, stream);

  gather_split<<<(STT * 64 * 256) / 256, 256, 0, stream>>>(text, emb, xp_hi, xp_lo, STT);
  gather_split<<<(SLL * 64 * 256) / 256, 256, 0, stream>>>(label, emb, xh_hi, xh_lo, SLL);

  PArgs cx;
  for (int s = 0; s < 4; ++s) {
    cx.xhi[s] = (s < 2) ? xp_hi : xh_hi;
    cx.xlo[s] = (s < 2) ? xp_lo : xh_lo;
    cx.mv[s] = nullptr;
    cx.whh[s] = (s & 1) ? cWhh_b : cWhh_f;
    cx.wih[s] = (s & 1) ? cWih_b : cWih_f;
    cx.bih[s] = (s & 1) ? cbih_b : cbih_f;
    cx.bhh[s] = (s & 1) ? cbhh_b : cbhh_f;
    cx.hx[s] = hxbase + (size_t)s * 2 * HB;
    cx.T[s] = (s < 2) ? STT : SLL;
    cx.dir[s] = s & 1;
  }
  cx.hs[0] = hs_pf; cx.hs[1] = hs_pb; cx.hs[2] = hs_hf; cx.hs[3] = hs_hb;
  cx.sync = sync_ctx;
  lstm_persist<0><<<32, 256, 0, stream>>>(cx);

  mv_match<<<STT / 4, 256, 0, stream>>>(hs_pf, hs_pb, hs_hf + (size_t)(SLL - 1) * HB,
                                        hs_hb + (size_t)(SLL - 1) * HB, w1, w2, mv_p, STT);
  mv_match<<<SLL / 4, 256, 0, stream>>>(hs_hf, hs_hb, hs_pf + (size_t)(STT - 1) * HB,
                                        hs_pb + (size_t)(STT - 1) * HB, w1, w2, mv_h, SLL);

  PArgs ag;
  for (int s = 0; s < 4; ++s) {
    ag.xhi[s] = nullptr;
    ag.xlo[s] = nullptr;
    ag.mv[s] = (s < 2) ? mv_p : mv_h;
    ag.whh[s] = (s & 1) ? aWhh_b : aWhh_f;
    ag.wih[s] = (s & 1) ? aWih_b : aWih_f;
    ag.bih[s] = (s & 1) ? abih_b : abih_f;
    ag.bhh[s] = (s & 1) ? abhh_b : abhh_f;
    ag.hx[s] = hxbase + (size_t)(4 + s) * 2 * HB;
    ag.T[s] = (s < 2) ? STT : SLL;
    ag.dir[s] = s & 1;
  }
  // agg writes hs only at t=T-1 (finals); reuse ctx hs buffers
  ag.hs[0] = hs_pf; ag.hs[1] = hs_pb; ag.hs[2] = hs_hf; ag.hs[3] = hs_hb;
  ag.sync = sync_agg;
  lstm_persist<1><<<32, 256, 0, stream>>>(ag);

  final_fc<<<BB, 256, 0, stream>>>(hs_pf + (size_t)(STT - 1) * HB,
                                   hs_pb + (size_t)(STT - 1) * HB,
                                   hs_hf + (size_t)(SLL - 1) * HB,
                                   hs_hb + (size_t)(SLL - 1) * HB,
                                   fc1W, fc1b, fc2W, fc2b, out);
}

// Round 8
// 15957.895 us; speedup vs baseline: 1.0031x; 1.0005x over previous
//
#include <hip/hip_runtime.h>
#include <math.h>

#define BB 64
#define STT 512
#define SLL 64
#define DD 256
#define HH 256
#define HB 16384  // HH*BB elements per h-slab

typedef __bf16 v8bf __attribute__((ext_vector_type(8)));
typedef float f32x16 __attribute__((ext_vector_type(16)));
typedef unsigned long long u64;

#define MFMA(a, b, c) __builtin_amdgcn_mfma_f32_32x32x16_bf16(a, b, c, 0, 0, 0)

__device__ __forceinline__ float sigm(float x) { return 1.0f / (1.0f + __expf(-x)); }
__device__ __forceinline__ v8bf ldv(const __bf16* p) { return *(const v8bf*)p; }
__device__ __forceinline__ __bf16 bfbits(unsigned short u) {
  return __builtin_bit_cast(__bf16, u);
}

__device__ __forceinline__ void unpack8(uint4 qa, uint4 qb, v8bf& hi, v8bf& lo) {
  unsigned wa[4] = {qa.x, qa.y, qa.z, qa.w};
  unsigned wb[4] = {qb.x, qb.y, qb.z, qb.w};
#pragma unroll
  for (int e = 0; e < 4; ++e) {
    hi[e] = bfbits((unsigned short)(wa[e] & 0xffff));
    lo[e] = bfbits((unsigned short)(wa[e] >> 16));
    hi[4 + e] = bfbits((unsigned short)(wb[e] & 0xffff));
    lo[4 + e] = bfbits((unsigned short)(wb[e] >> 16));
  }
}

struct PArgs {
  const __bf16* xhi[4];
  const __bf16* xlo[4];
  const float* mv[4];
  const float* whh[4];
  const float* wih[4];
  const float* bih[4];
  const float* bhh[4];
  float* hs[4];
  unsigned* hx[4];  // packed (lo<<16 | hi) bf16 pair, [2 slots][B][HH]
  unsigned* sync;   // per-kernel 4KB; stream s uses u32 [s*256 .. s*256+256)
  int T[4];
  int dir[4];
};

// Persistent BiLSTM. Grid = 32 blocks x 256 threads.
// stream s = blockIdx&3, unit-block jb = blockIdx>>2 (32 hidden units each).
// No placement assumptions: h exchange + step barrier use agent-scope atomics
// (correct across XCDs; round-2-validated protocol). Weights stay in VGPR/AGPR
// as split-bf16 MFMA B-fragments. h_{t-1} staged to LDS once per block per
// step (single 64KB MLP'd load, kills 4x per-wave redundancy). For ctx
// (XMODE 0) the x-projection MFMAs for step t+1 run between signal(t) and
// poll(t) to hide peers' latency.
template <int XMODE>
__global__ __launch_bounds__(256, 1) void lstm_persist(PArgs A) {
  const int s = blockIdx.x & 3;
  const int jb = blockIdx.x >> 2;
  const int T = A.T[s];
  const int dir = A.dir[s];
  const int tid = threadIdx.x;
  const int lane = tid & 63;
  const int g = tid >> 6;              // gate type of this wave
  const int l31 = lane & 31;
  const int khalf = (lane >> 5) << 3;  // 0 or 8 (A-frag k-offset)
  const int u_base = jb * 32;

  __shared__ u64 stage64[64][128];     // h_{t-1}, XOR-swizzled 16B granules
  __shared__ float lds_g[4][64][32];
  __shared__ float bias_s[4][32];
  __shared__ float w0_s[4][32];
  __shared__ float w1_s[4][32];

  if (tid < 128) {
    int gg = tid >> 5, uu = tid & 31;
    int row = gg * 256 + u_base + uu;
    bias_s[gg][uu] = A.bih[s][row] + A.bhh[s][row];
    if (XMODE == 1) {
      w0_s[gg][uu] = A.wih[s][row * 2 + 0];
      w1_s[gg][uu] = A.wih[s][row * 2 + 1];
    }
  }

  // ---- register-resident split-bf16 B-fragments (Whh; Wih too for ctx) ----
  v8bf whhhi[16], whhlo[16], wihhi[16], wihlo[16];
  {
    const int row = g * 256 + u_base + l31;
    const float* rp = A.whh[s] + (size_t)row * 256 + khalf;
#pragma unroll
    for (int kt = 0; kt < 16; ++kt) {
      float4 q0 = *(const float4*)(rp + kt * 16);
      float4 q1 = *(const float4*)(rp + kt * 16 + 4);
      float vv[8] = {q0.x, q0.y, q0.z, q0.w, q1.x, q1.y, q1.z, q1.w};
#pragma unroll
      for (int e = 0; e < 8; ++e) {
        __bf16 hh = (__bf16)vv[e];
        whhhi[kt][e] = hh;
        whhlo[kt][e] = (__bf16)(vv[e] - (float)hh);
      }
    }
    if (XMODE == 0) {
      const float* rq = A.wih[s] + (size_t)row * 256 + khalf;
#pragma unroll
      for (int kt = 0; kt < 16; ++kt) {
        float4 q0 = *(const float4*)(rq + kt * 16);
        float4 q1 = *(const float4*)(rq + kt * 16 + 4);
        float vv[8] = {q0.x, q0.y, q0.z, q0.w, q1.x, q1.y, q1.z, q1.w};
#pragma unroll
        for (int e = 0; e < 8; ++e) {
          __bf16 hh = (__bf16)vv[e];
          wihhi[kt][e] = hh;
          wihlo[kt][e] = (__bf16)(vv[e] - (float)hh);
        }
      }
    }
  }

  float c[8];
#pragma unroll
  for (int p = 0; p < 8; ++p) c[p] = 0.f;

  const int u = tid & 31, bb0 = tid >> 5;  // combine-phase mapping
  unsigned* slots = A.sync + s * 256;      // 8 slots, 32 u32 (128B) apart

  // staging geometry: thread covers row r (batch), quarter q (32 u64)
  const int sr = tid >> 2;
  const int sq = tid & 3;

  // x-projection accumulators (ctx): computed one step ahead
  f32x16 xacc0 = (f32x16)(0.0f);
  f32x16 xacc1 = (f32x16)(0.0f);

  auto xproj = [&](int t, f32x16& xa0, f32x16& xa1) {
    const int m0 = (dir ? (T - 1 - t) : t) * 64;
    const __bf16* xh = A.xhi[s] + (size_t)m0 * 256;
    const __bf16* xl = A.xlo[s] + (size_t)m0 * 256;
#pragma unroll
    for (int kt = 0; kt < 16; ++kt) {
      const int ko = kt * 16 + khalf;
      v8bf xh0 = ldv(xh + (size_t)l31 * 256 + ko);
      v8bf xl0 = ldv(xl + (size_t)l31 * 256 + ko);
      v8bf xh1 = ldv(xh + (size_t)(l31 + 32) * 256 + ko);
      v8bf xl1 = ldv(xl + (size_t)(l31 + 32) * 256 + ko);
      xa0 = MFMA(xh0, wihhi[kt], xa0);
      xa0 = MFMA(xl0, wihhi[kt], xa0);
      xa0 = MFMA(xh0, wihlo[kt], xa0);
      xa1 = MFMA(xh1, wihhi[kt], xa1);
      xa1 = MFMA(xl1, wihhi[kt], xa1);
      xa1 = MFMA(xh1, wihlo[kt], xa1);
    }
  };

  __syncthreads();
  if (XMODE == 0) xproj(0, xacc0, xacc1);

  for (int t = 0; t < T; ++t) {
    f32x16 acc0 = xacc0;
    f32x16 acc1 = xacc1;

    if (t > 0) {
      // ---- wait for h_{t-1} from all 8 blocks of this stream ----
      const unsigned want = (unsigned)t;
      if (tid < 64) {
        for (;;) {
          unsigned v = __hip_atomic_load(&slots[(lane & 7) * 32], __ATOMIC_ACQUIRE,
                                         __HIP_MEMORY_SCOPE_AGENT);
          if (!__any(v < want)) break;
          __builtin_amdgcn_s_sleep(1);
        }
      }
      __syncthreads();

      // ---- stage h_{t-1} -> LDS (one 64KB load, 32 u64 MLP per thread) ----
      {
        const u64* hp = (const u64*)(A.hx[s] + ((t + 1) & 1) * HB) + sr * 128 + sq * 32;
        u64 v[32];
#pragma unroll
        for (int j = 0; j < 32; ++j)
          v[j] = __hip_atomic_load(hp + j, __ATOMIC_RELAXED, __HIP_MEMORY_SCOPE_AGENT);
#pragma unroll
        for (int j = 0; j < 32; j += 2) {
          int gi = (sq * 16 + (j >> 1)) ^ (sr & 7);
          stage64[sr][gi * 2] = v[j];
          stage64[sr][gi * 2 + 1] = v[j + 1];
        }
      }
      __syncthreads();

      // ---- h MFMAs from staged LDS ----
      const int rswz = l31 & 7;  // same for rows l31 and l31+32
#pragma unroll
      for (int kt = 0; kt < 16; ++kt) {
        const int gbase = kt * 4 + (khalf >> 2);
        const int g0 = (gbase ^ rswz) * 2;
        const int g1 = ((gbase + 1) ^ rswz) * 2;
        uint4 qa0 = *(const uint4*)&stage64[l31][g0];
        uint4 qb0 = *(const uint4*)&stage64[l31][g1];
        uint4 qa1 = *(const uint4*)&stage64[l31 + 32][g0];
        uint4 qb1 = *(const uint4*)&stage64[l31 + 32][g1];
        v8bf ah0, al0, ah1, al1;
        unpack8(qa0, qb0, ah0, al0);
        unpack8(qa1, qb1, ah1, al1);
        acc0 = MFMA(ah0, whhhi[kt], acc0);
        acc0 = MFMA(al0, whhhi[kt], acc0);
        acc0 = MFMA(ah0, whhlo[kt], acc0);
        acc1 = MFMA(ah1, whhhi[kt], acc1);
        acc1 = MFMA(al1, whhhi[kt], acc1);
        acc1 = MFMA(ah1, whhlo[kt], acc1);
      }
    }

    // C/D layout (32x32): col=lane&31, row=(r&3)+8*(r>>2)+4*(lane>>5)
#pragma unroll
    for (int r = 0; r < 16; ++r) {
      int m = (r & 3) + 8 * (r >> 2) + 4 * (lane >> 5);
      lds_g[g][m][l31] = acc0[r];
      lds_g[g][m + 32][l31] = acc1[r];
    }
    __syncthreads();

    unsigned* ho = A.hx[s] + (t & 1) * HB;
    float* hsout = A.hs[s] + (size_t)t * HB;
    const int t_eff = dir ? (T - 1 - t) : t;
#pragma unroll
    for (int p = 0; p < 8; ++p) {
      int b = p * 8 + bb0;
      float g0 = lds_g[0][b][u] + bias_s[0][u];
      float g1 = lds_g[1][b][u] + bias_s[1][u];
      float g2 = lds_g[2][b][u] + bias_s[2][u];
      float g3 = lds_g[3][b][u] + bias_s[3][u];
      if (XMODE == 1) {
        float m0 = A.mv[s][t_eff * 128 + b];
        float m1 = A.mv[s][t_eff * 128 + 64 + b];
        g0 += w0_s[0][u] * m0 + w1_s[0][u] * m1;
        g1 += w0_s[1][u] * m0 + w1_s[1][u] * m1;
        g2 += w0_s[2][u] * m0 + w1_s[2][u] * m1;
        g3 += w0_s[3][u] * m0 + w1_s[3][u] * m1;
      }
      float iv = sigm(g0), fv = sigm(g1), zv = tanhf(g2), ov = sigm(g3);
      float cn = fv * c[p] + iv * zv;
      c[p] = cn;
      float hv = ov * tanhf(cn);
      int ug = u_base + u;
      unsigned short hb_ = __builtin_bit_cast(unsigned short, (__bf16)hv);
      float hif = (float)bfbits(hb_);
      unsigned short lb_ = __builtin_bit_cast(unsigned short, (__bf16)(hv - hif));
      unsigned pack = ((unsigned)lb_ << 16) | (unsigned)hb_;
      __hip_atomic_store(&ho[(size_t)b * 256 + ug], pack, __ATOMIC_RELAXED,
                         __HIP_MEMORY_SCOPE_AGENT);
      if (XMODE == 0 || t == T - 1) hsout[(size_t)b * 256 + ug] = hv;
    }
    __syncthreads();  // drains each wave's agent stores (vmcnt(0) before barrier)

    // ---- signal own slot, then hide peers' latency behind x-projection ----
    if (tid == 0)
      __hip_atomic_store(&slots[jb * 32], (unsigned)(t + 1), __ATOMIC_RELEASE,
                         __HIP_MEMORY_SCOPE_AGENT);
    xacc0 = (f32x16)(0.0f);
    xacc1 = (f32x16)(0.0f);
    if (XMODE == 0 && t + 1 < T) xproj(t + 1, xacc0, xacc1);
  }
}

// x split-bf16 gather: xhi/xlo[m=t*64+b][k] = emb[tok[b][t]][k]
__global__ __launch_bounds__(256) void gather_split(const int* __restrict__ tok,
                                                    const float* __restrict__ emb,
                                                    __bf16* __restrict__ xhi,
                                                    __bf16* __restrict__ xlo, int T) {
  size_t idx = (size_t)blockIdx.x * 256 + threadIdx.x;
  int k = idx & 255;
  size_t m = idx >> 8;
  int b = (int)(m & 63);
  int t = (int)(m >> 6);
  int token = tok[b * T + t];
  float v = emb[(size_t)token * 256 + k];
  __bf16 h = (__bf16)v;
  xhi[idx] = h;
  xlo[idx] = (__bf16)(v - (float)h);
}

// hs layout: [t][b][256]. Thread b streams its 1KB row.
__global__ __launch_bounds__(256) void mv_match(const float* __restrict__ hsf,
                                                const float* __restrict__ hsb,
                                                const float* __restrict__ vf,
                                                const float* __restrict__ vb,
                                                const float* __restrict__ w1,
                                                const float* __restrict__ w2,
                                                float* __restrict__ mv, int T) {
  int b = threadIdx.x & 63;
  int t = blockIdx.x * 4 + (threadIdx.x >> 6);
  if (t >= T) return;
  {
    const float* v1 = hsf + ((size_t)t * 64 + b) * 256;
    const float* v2 = vf + (size_t)b * 256;
    float num = 0.f, na = 0.f, nb = 0.f;
#pragma unroll 4
    for (int k = 0; k < HH; ++k) {
      float w = w1[k];
      float av = w * v1[k];
      float bv = w * v2[k];
      num = fmaf(av, bv, num);
      na = fmaf(av, av, na);
      nb = fmaf(bv, bv, nb);
    }
    mv[((size_t)t * 2 + 0) * BB + b] = num / fmaxf(sqrtf(na) * sqrtf(nb), 1e-8f);
  }
  {
    const float* v1 = hsb + ((size_t)(T - 1 - t) * 64 + b) * 256;
    const float* v2 = vb + (size_t)b * 256;
    float num = 0.f, na = 0.f, nb = 0.f;
#pragma unroll 4
    for (int k = 0; k < HH; ++k) {
      float w = w2[k];
      float av = w * v1[k];
      float bv = w * v2[k];
      num = fmaf(av, bv, num);
      na = fmaf(av, av, na);
      nb = fmaf(bv, bv, nb);
    }
    mv[((size_t)t * 2 + 1) * BB + b] = num / fmaxf(sqrtf(na) * sqrtf(nb), 1e-8f);
  }
}

// finals layout: [b][256]
__global__ __launch_bounds__(256) void final_fc(const float* __restrict__ pf,
                                                const float* __restrict__ pb,
                                                const float* __restrict__ hf,
                                                const float* __restrict__ hb,
                                                const float* __restrict__ fc1W,
                                                const float* __restrict__ fc1b,
                                                const float* __restrict__ fc2W,
                                                const float* __restrict__ fc2b,
                                                float* __restrict__ out) {
  __shared__ float xs[1024];
  __shared__ float ys[512];
  int b = blockIdx.x;
  for (int i = threadIdx.x; i < 1024; i += 256) {
    const float* src = (i < 256) ? pf : (i < 512) ? pb : (i < 768) ? hf : hb;
    xs[i] = src[(size_t)b * 256 + (i & 255)];
  }
  __syncthreads();
  for (int o = threadIdx.x; o < 512; o += 256) {
    float acc = fc1b[o];
    const float* w = fc1W + (size_t)o * 1024;
#pragma unroll 4
    for (int k = 0; k < 1024; ++k) acc = fmaf(w[k], xs[k], acc);
    ys[o] = tanhf(acc);
  }
  __syncthreads();
  if (threadIdx.x < 20) {
    int o = threadIdx.x;
    float acc = fc2b[o];
    const float* w = fc2W + (size_t)o * 512;
#pragma unroll 4
    for (int k = 0; k < 512; ++k) acc = fmaf(w[k], ys[k], acc);
    out[b * 20 + o] = acc;
  }
}

__global__ void guard_fill(float* out, int n, float v) {
  int i = blockIdx.x * 256 + threadIdx.x;
  if (i < n) out[i] = v;
}

extern "C" void kernel_launch(void* const* d_in, const int* in_sizes, int n_in,
                              void* d_out, int out_size, void* d_ws, size_t ws_size,
                              hipStream_t stream) {
  const int* text = (const int*)d_in[0];
  const int* label = (const int*)d_in[1];
  const float* emb = (const float*)d_in[2];
  const float* cWih_f = (const float*)d_in[3];
  const float* cWhh_f = (const float*)d_in[4];
  const float* cbih_f = (const float*)d_in[5];
  const float* cbhh_f = (const float*)d_in[6];
  const float* cWih_b = (const float*)d_in[7];
  const float* cWhh_b = (const float*)d_in[8];
  const float* cbih_b = (const float*)d_in[9];
  const float* cbhh_b = (const float*)d_in[10];
  const float* w1 = (const float*)d_in[11];
  const float* w2 = (const float*)d_in[12];
  const float* aWih_f = (const float*)d_in[13];
  const float* aWhh_f = (const float*)d_in[14];
  const float* abih_f = (const float*)d_in[15];
  const float* abhh_f = (const float*)d_in[16];
  const float* aWih_b = (const float*)d_in[17];
  const float* aWhh_b = (const float*)d_in[18];
  const float* abih_b = (const float*)d_in[19];
  const float* abhh_b = (const float*)d_in[20];
  const float* fc1W = (const float*)d_in[21];
  const float* fc1b = (const float*)d_in[22];
  const float* fc2W = (const float*)d_in[23];
  const float* fc2b = (const float*)d_in[24];
  float* out = (float*)d_out;

  char* base = (char*)d_ws;
  size_t off = 0;
  auto alloc = [&](size_t bytes) {
    void* p = base + off;
    off = (off + bytes + 255) & ~(size_t)255;
    return p;
  };

  __bf16* xp_hi = (__bf16*)alloc((size_t)STT * 64 * 256 * 2);
  __bf16* xp_lo = (__bf16*)alloc((size_t)STT * 64 * 256 * 2);
  __bf16* xh_hi = (__bf16*)alloc((size_t)SLL * 64 * 256 * 2);
  __bf16* xh_lo = (__bf16*)alloc((size_t)SLL * 64 * 256 * 2);
  float* hs_pf = (float*)alloc((size_t)STT * HB * 4);
  float* hs_pb = (float*)alloc((size_t)STT * HB * 4);
  float* hs_hf = (float*)alloc((size_t)SLL * HB * 4);
  float* hs_hb = (float*)alloc((size_t)SLL * HB * 4);
  float* mv_p = (float*)alloc((size_t)STT * 2 * 64 * 4);
  float* mv_h = (float*)alloc((size_t)SLL * 2 * 64 * 4);
  // ---- zeroed-per-launch region: hx (8 stream-slots x 2 x HB u32) + sync ----
  size_t zero_off = off;
  unsigned* hxbase = (unsigned*)alloc((size_t)8 * 2 * HB * 4);
  unsigned* sync_ctx = (unsigned*)alloc(4096);
  unsigned* sync_agg = (unsigned*)alloc(4096);
  size_t zero_len = off - zero_off;

  if (ws_size < off) {
    guard_fill<<<(out_size + 255) / 256, 256, 0, stream>>>(out, out_size,
                                                           (float)(ws_size >> 20));
    return;
  }

  hipMemsetAsync(base + zero_off, 0, zero_len, stream);

  gather_split<<<(STT * 64 * 256) / 256, 256, 0, stream>>>(text, emb, xp_hi, xp_lo, STT);
  gather_split<<<(SLL * 64 * 256) / 256, 256, 0, stream>>>(label, emb, xh_hi, xh_lo, SLL);

  PArgs cx;
  for (int s = 0; s < 4; ++s) {
    cx.xhi[s] = (s < 2) ? xp_hi : xh_hi;
    cx.xlo[s] = (s < 2) ? xp_lo : xh_lo;
    cx.mv[s] = nullptr;
    cx.whh[s] = (s & 1) ? cWhh_b : cWhh_f;
    cx.wih[s] = (s & 1) ? cWih_b : cWih_f;
    cx.bih[s] = (s & 1) ? cbih_b : cbih_f;
    cx.bhh[s] = (s & 1) ? cbhh_b : cbhh_f;
    cx.hx[s] = hxbase + (size_t)s * 2 * HB;
    cx.T[s] = (s < 2) ? STT : SLL;
    cx.dir[s] = s & 1;
  }
  cx.hs[0] = hs_pf; cx.hs[1] = hs_pb; cx.hs[2] = hs_hf; cx.hs[3] = hs_hb;
  cx.sync = sync_ctx;
  lstm_persist<0><<<32, 256, 0, stream>>>(cx);

  mv_match<<<STT / 4, 256, 0, stream>>>(hs_pf, hs_pb, hs_hf + (size_t)(SLL - 1) * HB,
                                        hs_hb + (size_t)(SLL - 1) * HB, w1, w2, mv_p, STT);
  mv_match<<<SLL / 4, 256, 0, stream>>>(hs_hf, hs_hb, hs_pf + (size_t)(STT - 1) * HB,
                                        hs_pb + (size_t)(STT - 1) * HB, w1, w2, mv_h, SLL);

  PArgs ag;
  for (int s = 0; s < 4; ++s) {
    ag.xhi[s] = nullptr;
    ag.xlo[s] = nullptr;
    ag.mv[s] = (s < 2) ? mv_p : mv_h;
    ag.whh[s] = (s & 1) ? aWhh_b : aWhh_f;
    ag.wih[s] = (s & 1) ? aWih_b : aWih_f;
    ag.bih[s] = (s & 1) ? abih_b : abih_f;
    ag.bhh[s] = (s & 1) ? abhh_b : abhh_f;
    ag.hx[s] = hxbase + (size_t)(4 + s) * 2 * HB;
    ag.T[s] = (s < 2) ? STT : SLL;
    ag.dir[s] = s & 1;
  }
  // agg writes hs only at t=T-1 (finals); reuse ctx hs buffers
  ag.hs[0] = hs_pf; ag.hs[1] = hs_pb; ag.hs[2] = hs_hf; ag.hs[3] = hs_hb;
  ag.sync = sync_agg;
  lstm_persist<1><<<32, 256, 0, stream>>>(ag);

  final_fc<<<BB, 256, 0, stream>>>(hs_pf + (size_t)(STT - 1) * HB,
                                   hs_pb + (size_t)(STT - 1) * HB,
                                   hs_hf + (size_t)(SLL - 1) * HB,
                                   hs_hb + (size_t)(SLL - 1) * HB,
                                   fc1W, fc1b, fc2W, fc2b, out);
}